// Round 14
// baseline (349.537 us; speedup 1.0000x reference)
//
#include <hip/hip_runtime.h>
#include <hip/hip_bf16.h>
#include <math.h>

#define EPSF 1e-7f

typedef __attribute__((ext_vector_type(8))) short bhalf8;   // 8 bf16 (4 VGPRs)
typedef __attribute__((ext_vector_type(4))) float floatx4;  // MFMA acc

// ============================================================================
// prepc1 (R21): conv1 + all weight prep fused into ONE launch.
// conv1 = R15 form (LDS-broadcast weights + chunk-major stores).
// h1t layout: [img][chunk c16=oc/8][pos][8 oc], chunk stride 3600B.
// ============================================================================
__global__ __launch_bounds__(256) void prepc1_kernel(
    const float* __restrict__ x,      const float* __restrict__ conv1w,
    const float* __restrict__ conv1b, __hip_bfloat16* __restrict__ h1t,
    const float* __restrict__ conv2w, const float* __restrict__ conv3w,
    const float* __restrict__ capsw,  const float* __restrict__ fc1w,
    const float* __restrict__ fc2w,   const float* __restrict__ fc3w,
    __hip_bfloat16* __restrict__ wt2, __hip_bfloat16* __restrict__ wt3,
    __hip_bfloat16* __restrict__ cwt, float* __restrict__ fc1wt,
    __hip_bfloat16* __restrict__ wf2, __hip_bfloat16* __restrict__ wf3)
{
  __shared__ float sh[6400];            // 25.6 KB union
  const int t = threadIdx.x;
  int b = blockIdx.x;

  if (b < 512) {                        // ---- conv1 (R15): 2 img/block ----
    float* wl = sh;                     // [128 oc][32 taps padded]
    float* bl = sh + 4096;
    const int b0 = b * 2;
    for (int i = t; i < 4096; i += 256) {
      int oc = i >> 5, q = i & 31;
      wl[i] = (q < 27) ? conv1w[oc*27 + q] : 0.f;
    }
    if (t < 128) bl[t] = conv1b[t];
    __syncthreads();
    if (t >= 225) return;
    const int py = t / 15, px = t % 15;
    float win[2][28];
    win[0][27] = 0.f; win[1][27] = 0.f;
#pragma unroll
    for (int im = 0; im < 2; ++im) {
      const float* xb = x + (size_t)(b0 + im) * 3072;
#pragma unroll
      for (int c = 0; c < 3; ++c)
#pragma unroll
        for (int ky = 0; ky < 3; ++ky)
#pragma unroll
          for (int kx = 0; kx < 3; ++kx)
            win[im][c*9 + ky*3 + kx] = xb[c*1024 + (py*2 + ky)*32 + (px*2 + kx)];
    }
#pragma unroll 1
    for (int oc0 = 0; oc0 < 128; oc0 += 32) {
      __hip_bfloat16 hv[2][32];
#pragma unroll
      for (int oc = 0; oc < 32; ++oc) {
        const float4* wp = (const float4*)&wl[(oc0 + oc) << 5];  // uniform
        float a0 = bl[oc0 + oc], a1 = a0;
#pragma unroll
        for (int qq = 0; qq < 7; ++qq) {
          float4 wv = wp[qq];                                     // b128 bcast
          a0 = fmaf(win[0][qq*4+0], wv.x, a0); a1 = fmaf(win[1][qq*4+0], wv.x, a1);
          a0 = fmaf(win[0][qq*4+1], wv.y, a0); a1 = fmaf(win[1][qq*4+1], wv.y, a1);
          a0 = fmaf(win[0][qq*4+2], wv.z, a0); a1 = fmaf(win[1][qq*4+2], wv.z, a1);
          a0 = fmaf(win[0][qq*4+3], wv.w, a0); a1 = fmaf(win[1][qq*4+3], wv.w, a1);
        }
        hv[0][oc] = __float2bfloat16(fmaxf(a0, 0.f));
        hv[1][oc] = __float2bfloat16(fmaxf(a1, 0.f));
      }
#pragma unroll
      for (int qq = 0; qq < 4; ++qq) {
        int c16 = (oc0 >> 3) + qq;            // 16B chunk = 8 oc
#pragma unroll
        for (int im = 0; im < 2; ++im) {
          const uint4* src = (const uint4*)hv[im];
          *(uint4*)((char*)h1t + (size_t)(b0+im)*57600 + c16*3600 + t*16) = src[qq];
        }
      }
    }
    return;
  }
  b -= 512;
  if (b < 12288) {                      // fc3_w cast: 3,145,728
    int i = b*256 + t;
    wf3[i] = __float2bfloat16(fc3w[i]);
    return;
  }
  b -= 12288;
  if (b < 2048) {                       // fc2_w cast: 524,288
    int i = b*256 + t;
    wf2[i] = __float2bfloat16(fc2w[i]);
    return;
  }
  b -= 2048;
  if (b < 640) {                        // caps_w transpose: 163,840
    int i2 = b*256 + t;
    int k = i2 & 15, j = (i2 >> 4) & 15, io = i2 >> 8;
    cwt[i2] = __float2bfloat16(capsw[(io*16 + k)*16 + j]);
    return;
  }
  b -= 640;
  if (b < 320) {                        // fc1_w transpose: 81,920
    int i = b*256 + t;
    int j = i >> 9, n = i & 511;
    fc1wt[i] = fc1w[n*160 + j];
    return;
  }
  b -= 320;
  if (b < 256) {                        // wtrans3: one oc per block
    float* tl = sh;
    const float* src = conv3w + (size_t)b*6400;   // contiguous per oc
    for (int i = t; i < 6400; i += 256) tl[i] = src[i];
    __syncthreads();
#pragma unroll 1
    for (int q = 0; q < 25; ++q) {
      int j = q*256 + t;                // flat k = s*64+kq = j
      int s = j >> 6, kq = j & 63;
      int tap = j >> 8, ic = j & 255;
      wt3[(size_t)s*16384 + b*64 + kq] = __float2bfloat16(tl[ic*25 + tap]);
    }
    return;
  }
  b -= 256;
  {                                     // wtrans2: one oc per block (256)
    float* tl = sh;
    const float* src = conv2w + (size_t)b*3200;   // contiguous per oc
    for (int i = t; i < 3200; i += 256) tl[i] = src[i];
    __syncthreads();
#pragma unroll 1
    for (int q = 0; q < 13; ++q) {
      int j = q*256 + t;
      if (j < 3200) {
        int s = j >> 5, kq = j & 31;
        int h = (s >= 50) ? 1 : 0;
        int r2 = s - h*50;
        int tap = r2 >> 1, qq = r2 & 1;
        int ic = h*64 + qq*32 + kq;
        wt2[(size_t)s*8192 + b*32 + kq] = __float2bfloat16(tl[ic*25 + tap]);
      }
    }
  }
}

// ============================================================================
// conv2_mfma_v6 (R22): 768 thr = 12 waves = 3wm x 4wn, Nt=4, 4 img/block,
// 256 blocks (1/CU). The unexplored geometry corner:
//  - A-reads/tap = 12x3 = 36 (HALF of v2's 72) -> LDS term 36 -> 18 us
//  - 9 M-tiles = 144 rows EXACT (no padding, no wm conditional)
//  - B-issue 48/step (1.5x v2, not the 2x that killed R14's 4wm)
//  - 3 waves/SIMD (not the 2 that killed the 8-wave variant)
//  - VGPR need ~56 (proven by R14's identical Nt=4 reg structure) under
//    the 768-thr worst-case cap of 85 -> no spill expected.
// Same proven-uniform swizzle: slot = (g + m + dsw) & 7.
// ============================================================================
__global__ __launch_bounds__(768) void conv2_mfma_v6_kernel(
    const __hip_bfloat16* __restrict__ a,   // h1t chunk-major
    const __hip_bfloat16* __restrict__ wt,  // wt2 dense [100][256][32]
    const float* __restrict__ bias,
    __hip_bfloat16* __restrict__ out)       // h2t [1024][36][256]
{
  __shared__ __align__(16) unsigned short Il[4*225*64];   // 115,200 B
  const int b0   = blockIdx.x * 4;
  const int t    = threadIdx.x;
  const int lane = t & 63;
  const int w    = t >> 6;        // 0..11
  const int wm   = w >> 2;        // 0..2 : tiles wm*3 .. wm*3+2
  const int wn   = w & 3;         // 0..3 : oc group wn*64 (Nt=4)
  const int n    = lane & 15;
  const int g    = lane >> 4;

  // B: step s slice = 16,384 B = [256 oc][32 k]; lane reads
  // oc = wn*64 + nt*16 + n, k = g*8..g*8+7. nt offset = +1024 B.
  const char* gB = (const char*)wt + (wn*64 + n)*64 + g*16;
  bhalf8 bs0[4], bs1[4];          // distance-2 slot sets x 4 nt
#pragma unroll
  for (int nt = 0; nt < 4; ++nt) {
    bs0[nt] = *(const bhalf8*)(gB + nt*1024);             // s=0
    bs1[nt] = *(const bhalf8*)(gB + 16384 + nt*1024);     // s=1
  }

  // ---- per-lane M geometry: tile = wm*3 + mt, all 9 tiles valid ----
  int Abase[3], em[3];
#pragma unroll
  for (int mt = 0; mt < 3; ++mt) {
    int tile = wm*3 + mt;
    int m = tile*16 + n;                 // 0..143, always valid
    int img = m / 36, pos = m - img*36;
    int py = pos / 6, px = pos - py*6;
    int pixb = 30*py + 2*px;             // always even
    Abase[mt] = (img*225 + pixb) * 128;  // bytes (row = 64 ic = 128 B)
    em[mt] = g + m;                      // slot seed: (g + m + dsw) & 7
  }

  floatx4 acc[3][4];
#pragma unroll
  for (int mt = 0; mt < 3; ++mt)
#pragma unroll
    for (int nt = 0; nt < 4; ++nt)
      acc[mt][nt] = (floatx4){0.f, 0.f, 0.f, 0.f};

  int s = 0;
#pragma unroll 1
  for (int h = 0; h < 2; ++h) {
    if (h) __syncthreads();              // pass-0 reads done before overwrite
    // ---- stage 4 img x 225 pix x 64-ic half h (chunk-major h1t) ----
    for (int i = t; i < 7200; i += 768) {
      int img = i / 1800;
      int r = i - img*1800;
      int p = r >> 3, c = r & 7;
      uint4 v = *(const uint4*)((const char*)a +
                (size_t)(b0+img)*57600 + (h*8 + c)*3600 + p*16);
      int px15 = p % 15, py15 = p / 15;
      int csw = (c + (px15 >> 1) + 6*(py15 >> 1) + ((img & 1) << 2)) & 7;
      *(uint4*)((char*)Il + (img*225 + p)*128 + csw*16) = v;
    }
    __syncthreads();

    int dpix = 0, kx = 0, ky = 0;        // dpix = ky*15 + kx
#pragma unroll 1
    for (int tap = 0; tap < 25; ++tap) {
      const int doff = dpix << 7;
      const int dsw  = (kx >> 1) + 6*(ky >> 1);
      int a0[3];
#pragma unroll
      for (int mt = 0; mt < 3; ++mt)
        a0[mt] = Abase[mt] + doff + (((em[mt] + dsw) & 7) << 4);

      // ---- q = 0: each av feeds 4 MFMAs ----
#pragma unroll
      for (int mt = 0; mt < 3; ++mt) {
        bhalf8 av = *(const bhalf8*)((const char*)Il + a0[mt]);
#pragma unroll
        for (int nt = 0; nt < 4; ++nt)
          acc[mt][nt] = __builtin_amdgcn_mfma_f32_16x16x32_bf16(av, bs0[nt], acc[mt][nt], 0, 0, 0);
      }
      {
        const int spre = (s + 2 < 100) ? (s + 2) : 99;
#pragma unroll
        for (int nt = 0; nt < 4; ++nt)
          bs0[nt] = *(const bhalf8*)(gB + (size_t)spre*16384 + nt*1024);
      }
      // ---- q = 1: slot +4 mod 8 == addr ^ 64 ----
#pragma unroll
      for (int mt = 0; mt < 3; ++mt) {
        bhalf8 av = *(const bhalf8*)((const char*)Il + (a0[mt] ^ 64));
#pragma unroll
        for (int nt = 0; nt < 4; ++nt)
          acc[mt][nt] = __builtin_amdgcn_mfma_f32_16x16x32_bf16(av, bs1[nt], acc[mt][nt], 0, 0, 0);
      }
      {
        const int spre = (s + 3 < 100) ? (s + 3) : 99;
#pragma unroll
        for (int nt = 0; nt < 4; ++nt)
          bs1[nt] = *(const bhalf8*)(gB + (size_t)spre*16384 + nt*1024);
      }
      s += 2;
      if (kx == 4) { kx = 0; ++ky; dpix += 11; } else { ++kx; ++dpix; }
    }
  }

  // ---- epilogue: D row = g*4+r, col = n. All 144 rows valid. ----
  float bv[4];
#pragma unroll
  for (int nt = 0; nt < 4; ++nt) bv[nt] = bias[wn*64 + nt*16 + n];
#pragma unroll
  for (int mt = 0; mt < 3; ++mt) {
    int tile = wm*3 + mt;
#pragma unroll
    for (int r = 0; r < 4; ++r) {
      int m = tile*16 + g*4 + r;
      int img = m / 36, pos = m - img*36;
      size_t o = (((size_t)(b0+img)*36 + pos) << 8) + wn*64 + n;
#pragma unroll
      for (int nt = 0; nt < 4; ++nt)
        out[o + nt*16] = __float2bfloat16(fmaxf(acc[mt][nt][r] + bv[nt], 0.f));
    }
  }
}

// ============================================================================
// conv3_mfma (split-K): h2t -> fp32 partials pout[8][1024][256][4].
// ============================================================================
__global__ __launch_bounds__(512) void conv3_mfma_kernel(
    const __hip_bfloat16* __restrict__ a,   // h2t [1024][36][256]
    const __hip_bfloat16* __restrict__ wt,  // wt3 dense [100][256][64]
    float* __restrict__ pout)               // [8][1024*1024]
{
  __shared__ __align__(16) unsigned short Il[16*1448];    // 46,336 B
  const int b0   = blockIdx.x * 16;
  const int kq   = blockIdx.y;             // ic slice kq*32..+31
  const int t    = threadIdx.x;
  const int lane = t & 63;
  const int w    = t >> 6;                 // 0..7 -> oc w*32
  const int n    = lane & 15;
  const int g    = lane >> 4;

  for (int i = t; i < 2304; i += 512) {    // 16*36*4 chunks of 16B
    int img = i / 144, r = i - img*144;
    int p = r >> 2, c = r & 3;
    uint4 v = *(const uint4*)((const char*)a +
              ((((size_t)(b0+img)*36 + p) << 9) + kq*64 + c*16));
    *(uint4*)((char*)Il + (img*1448 + p*40 + c*8)*2) = v;
  }

  const char* gB = (const char*)wt + (size_t)(w*32 + n)*128 +
                   (kq & 1)*64 + g*16;
  const int kqs = kq >> 1;
  bhalf8 b00, b01, b10, b11;
  b00 = *(const bhalf8*)(gB + (size_t)(0*4 + kqs)*32768);
  b01 = *(const bhalf8*)(gB + (size_t)(0*4 + kqs)*32768 + 2048);
  b10 = *(const bhalf8*)(gB + (size_t)(1*4 + kqs)*32768);
  b11 = *(const bhalf8*)(gB + (size_t)(1*4 + kqs)*32768 + 2048);

  const int d = n >> 2, pos = n & 3;
  const int pb = (pos >> 1)*6 + (pos & 1);
  int ab[4];
#pragma unroll
  for (int mt = 0; mt < 4; ++mt)
    ab[mt] = ((mt*4 + d)*1448 + pb*40 + g*8) * 2;   // bytes

  floatx4 acc[4][2];
#pragma unroll
  for (int mt = 0; mt < 4; ++mt)
#pragma unroll
    for (int nt = 0; nt < 2; ++nt)
      acc[mt][nt] = (floatx4){0.f, 0.f, 0.f, 0.f};

  __syncthreads();   // the ONLY barrier

  int toff = 0, kx = 0;
#pragma unroll 1
  for (int tap = 0; tap < 24; tap += 2) {
#pragma unroll
    for (int mt = 0; mt < 4; ++mt) {
      bhalf8 av = *(const bhalf8*)((const char*)Il + ab[mt] + toff*80);
      acc[mt][0] = __builtin_amdgcn_mfma_f32_16x16x32_bf16(av, b00, acc[mt][0], 0, 0, 0);
      acc[mt][1] = __builtin_amdgcn_mfma_f32_16x16x32_bf16(av, b01, acc[mt][1], 0, 0, 0);
    }
    b00 = *(const bhalf8*)(gB + (size_t)((tap+2)*4 + kqs)*32768);
    b01 = *(const bhalf8*)(gB + (size_t)((tap+2)*4 + kqs)*32768 + 2048);
    if (++kx == 5) { kx = 0; toff += 2; } else ++toff;
#pragma unroll
    for (int mt = 0; mt < 4; ++mt) {
      bhalf8 av = *(const bhalf8*)((const char*)Il + ab[mt] + toff*80);
      acc[mt][0] = __builtin_amdgcn_mfma_f32_16x16x32_bf16(av, b10, acc[mt][0], 0, 0, 0);
      acc[mt][1] = __builtin_amdgcn_mfma_f32_16x16x32_bf16(av, b11, acc[mt][1], 0, 0, 0);
    }
    {
      const int tpre = (tap + 3 <= 24) ? (tap + 3) : 24;
      b10 = *(const bhalf8*)(gB + (size_t)(tpre*4 + kqs)*32768);
      b11 = *(const bhalf8*)(gB + (size_t)(tpre*4 + kqs)*32768 + 2048);
    }
    if (++kx == 5) { kx = 0; toff += 2; } else ++toff;
  }
#pragma unroll
  for (int mt = 0; mt < 4; ++mt) {
    bhalf8 av = *(const bhalf8*)((const char*)Il + ab[mt] + toff*80);
    acc[mt][0] = __builtin_amdgcn_mfma_f32_16x16x32_bf16(av, b00, acc[mt][0], 0, 0, 0);
    acc[mt][1] = __builtin_amdgcn_mfma_f32_16x16x32_bf16(av, b01, acc[mt][1], 0, 0, 0);
  }

  float* po = pout + (size_t)kq*1048576;
#pragma unroll
  for (int mt = 0; mt < 4; ++mt) {
#pragma unroll
    for (int r = 0; r < 4; ++r) {
      int m = mt*16 + g*4 + r;
      int img = m >> 2, p2 = m & 3;
#pragma unroll
      for (int nt = 0; nt < 2; ++nt)
        po[((size_t)(b0+img)*256 + w*32 + nt*16 + n)*4 + p2] = acc[mt][nt][r];
    }
  }
}

// ============================================================================
// caps: sum 8 conv3 partials + bias + ReLU -> squash -> u_hat -> routing
// -> v_lengths + fused fc1.
// ============================================================================
__global__ __launch_bounds__(256) void caps_kernel(
    const float* __restrict__ pout, const __hip_bfloat16* __restrict__ cwt,
    const float* __restrict__ cb, const float* __restrict__ c3b,
    const int* __restrict__ y,
    const float* __restrict__ fc1wt, const float* __restrict__ fc1b,
    float* __restrict__ vlen, __hip_bfloat16* __restrict__ h1f)
{
  __shared__ float prim[1024];     // [64][16]
  __shared__ float uh[10240];      // [64][10][16]
  __shared__ float bij[640];
  __shared__ float cij[640];
  __shared__ float vv[160];        // [10][16]
  const int b = blockIdx.x, t = threadIdx.x;
  {
    const float* pp = pout + (size_t)b*1024 + t*4;
    float4 s4 = *(const float4*)pp;
#pragma unroll
    for (int q = 1; q < 8; ++q) {
      float4 v = *(const float4*)(pp + (size_t)q*1048576);
      s4.x += v.x; s4.y += v.y; s4.z += v.z; s4.w += v.w;
    }
    const float bv = c3b[t];       // oc = t
    float4 h = make_float4(fmaxf(s4.x + bv, 0.f), fmaxf(s4.y + bv, 0.f),
                           fmaxf(s4.z + bv, 0.f), fmaxf(s4.w + bv, 0.f));
    float dd = h.x*h.x + h.y*h.y + h.z*h.z + h.w*h.w;
    dd += __shfl_xor(dd, 1);
    dd += __shfl_xor(dd, 2);
    float sc = dd / (1.f + dd) / sqrtf(dd + EPSF);
    float4 o4 = make_float4(h.x*sc, h.y*sc, h.z*sc, h.w*sc);
    *(float4*)&prim[t*4] = o4;     // prim flat elem = t*4..t*4+3
  }
  for (int f = t; f < 640; f += 256) bij[f] = 0.f;
  __syncthreads();
  for (int f = t; f < 10240; f += 256) {
    const int i = f / 160;
    const uint4* wv = (const uint4*)(cwt + (size_t)f*16);
    uint4 wa = wv[0], wb = wv[1];
    unsigned uw[8] = {wa.x, wa.y, wa.z, wa.w, wb.x, wb.y, wb.z, wb.w};
    const float* pp = prim + i*16;
    float s = 0.f;
#pragma unroll
    for (int q = 0; q < 8; ++q) {
      float lo = __uint_as_float(uw[q] << 16);
      float hi = __uint_as_float(uw[q] & 0xffff0000u);
      s = fmaf(pp[2*q],   lo, s);
      s = fmaf(pp[2*q+1], hi, s);
    }
    uh[f] = s;
  }
  __syncthreads();
  for (int r = 0; r < 3; ++r) {
    if (t < 64) {
      float e[10];
      float mx = -1e30f;
#pragma unroll
      for (int o = 0; o < 10; ++o) { e[o] = bij[t*10 + o]; mx = fmaxf(mx, e[o]); }
      float sum = 0.f;
#pragma unroll
      for (int o = 0; o < 10; ++o) { e[o] = expf(e[o] - mx); sum += e[o]; }
      float inv = 1.f / sum;
#pragma unroll
      for (int o = 0; o < 10; ++o) cij[t*10 + o] = e[o] * inv;
    }
    __syncthreads();
    if (t < 160) {
      const int o = t >> 4;
      float s0 = cb[t], s1 = 0.f, s2 = 0.f, s3 = 0.f;
      for (int i = 0; i < 64; i += 4) {
        s0 = fmaf(cij[(i+0)*10 + o], uh[(i+0)*160 + t], s0);
        s1 = fmaf(cij[(i+1)*10 + o], uh[(i+1)*160 + t], s1);
        s2 = fmaf(cij[(i+2)*10 + o], uh[(i+2)*160 + t], s2);
        s3 = fmaf(cij[(i+3)*10 + o], uh[(i+3)*160 + t], s3);
      }
      float s = (s0 + s1) + (s2 + s3);
      float dd = s*s;
      dd += __shfl_xor(dd, 1); dd += __shfl_xor(dd, 2);
      dd += __shfl_xor(dd, 4); dd += __shfl_xor(dd, 8);
      float sc = dd / (1.f + dd) / sqrtf(dd + EPSF);
      vv[t] = s * sc;
      if (r == 2 && (t & 15) == 0)
        vlen[b*10 + o] = sqrtf(sc*sc*dd + EPSF);
    }
    __syncthreads();
    if (r < 2) {
      for (int f = t; f < 640; f += 256) {
        int i = f / 10, o = f % 10;
        const float* up = &uh[i*160 + o*16];
        const float* vp = &vv[o*16];
        float a = 0.f;
#pragma unroll
        for (int j = 0; j < 16; ++j) a = fmaf(up[j], vp[j], a);
        bij[f] += a;
      }
      __syncthreads();
    }
  }
  const int yb = y[b];
  const float* vy = &vv[yb*16];
  for (int nn = t; nn < 512; nn += 256) {
    float s = fc1b[nn];
#pragma unroll
    for (int k = 0; k < 16; ++k)
      s = fmaf(vy[k], fc1wt[(yb*16 + k)*512 + nn], s);
    h1f[b*512 + nn] = __float2bfloat16(fmaxf(s, 0.f));
  }
}

// ============================================================================
// fc_mfma: out = act(A[M,K]bf16 @ W[N,K]bf16^T + bias). Pure-register GEMM.
// ============================================================================
template<int ACT, int MT, int NT>
__global__ __launch_bounds__(256) void fc_mfma_kernel(
    const __hip_bfloat16* __restrict__ A,   // [M,K]
    const __hip_bfloat16* __restrict__ W,   // [N,K]
    const float* __restrict__ bias,
    void* __restrict__ outv, int M, int N, int K)
{
  const int t    = threadIdx.x;
  const int lane = t & 63;
  const int w    = t >> 6;
  const int wr   = w >> 1, wc = w & 1;
  const int n    = lane & 15, g = lane >> 4;
  const int m0   = blockIdx.x * (2*MT*16) + wr*(MT*16);
  const int n0   = blockIdx.y * (2*NT*16) + wc*(NT*16);
  const __hip_bfloat16* Ap = A + (size_t)(m0 + n)*K + g*8;
  const __hip_bfloat16* Wp = W + (size_t)(n0 + n)*K + g*8;
  const int steps = K >> 5;

  bhalf8 aa0[MT], aa1[MT], bb0[NT], bb1[NT];
#pragma unroll
  for (int mt = 0; mt < MT; ++mt) {
    aa0[mt] = *(const bhalf8*)(Ap + (size_t)mt*16*K);
    aa1[mt] = *(const bhalf8*)(Ap + (size_t)mt*16*K + 32);
  }
#pragma unroll
  for (int nt = 0; nt < NT; ++nt) {
    bb0[nt] = *(const bhalf8*)(Wp + (size_t)nt*16*K);
    bb1[nt] = *(const bhalf8*)(Wp + (size_t)nt*16*K + 32);
  }

  floatx4 acc[MT][NT];
#pragma unroll
  for (int mt = 0; mt < MT; ++mt)
#pragma unroll
    for (int nt = 0; nt < NT; ++nt)
      acc[mt][nt] = (floatx4){0.f, 0.f, 0.f, 0.f};

#pragma unroll 1
  for (int s = 0; s < steps; s += 2) {
#pragma unroll
    for (int mt = 0; mt < MT; ++mt)
#pragma unroll
      for (int nt = 0; nt < NT; ++nt)
        acc[mt][nt] = __builtin_amdgcn_mfma_f32_16x16x32_bf16(
            aa0[mt], bb0[nt], acc[mt][nt], 0, 0, 0);
    {
      const int spre = (s + 2 < steps) ? (s + 2) : s;
#pragma unroll
      for (int mt = 0; mt < MT; ++mt)
        aa0[mt] = *(const bhalf8*)(Ap + (size_t)mt*16*K + spre*32);
#pragma unroll
      for (int nt = 0; nt < NT; ++nt)
        bb0[nt] = *(const bhalf8*)(Wp + (size_t)nt*16*K + spre*32);
    }
#pragma unroll
    for (int mt = 0; mt < MT; ++mt)
#pragma unroll
      for (int nt = 0; nt < NT; ++nt)
        acc[mt][nt] = __builtin_amdgcn_mfma_f32_16x16x32_bf16(
            aa1[mt], bb1[nt], acc[mt][nt], 0, 0, 0);
    {
      const int spre = (s + 3 < steps) ? (s + 3) : (s + 1);
#pragma unroll
      for (int mt = 0; mt < MT; ++mt)
        aa1[mt] = *(const bhalf8*)(Ap + (size_t)mt*16*K + spre*32);
#pragma unroll
      for (int nt = 0; nt < NT; ++nt)
        bb1[nt] = *(const bhalf8*)(Wp + (size_t)nt*16*K + spre*32);
    }
  }

#pragma unroll
  for (int mt = 0; mt < MT; ++mt) {
#pragma unroll
    for (int r = 0; r < 4; ++r) {
      const int m = m0 + mt*16 + g*4 + r;
#pragma unroll
      for (int nt = 0; nt < NT; ++nt) {
        const int col = n0 + nt*16 + n;
        float v = acc[mt][nt][r] + bias[col];
        if (ACT == 0) {
          ((__hip_bfloat16*)outv)[(size_t)m*N + col] =
              __float2bfloat16(fmaxf(v, 0.f));
        } else {
          ((float*)outv)[(size_t)m*N + col] = 1.f / (1.f + expf(-v));
        }
      }
    }
  }
}

// ============================================================================
extern "C" void kernel_launch(void* const* d_in, const int* in_sizes, int n_in,
                              void* d_out, int out_size, void* d_ws, size_t ws_size,
                              hipStream_t stream) {
  const float* x       = (const float*)d_in[0];
  const int*   y       = (const int*)  d_in[1];
  const float* conv1_w = (const float*)d_in[2];
  const float* conv1_b = (const float*)d_in[3];
  const float* conv2_w = (const float*)d_in[4];
  const float* conv2_b = (const float*)d_in[5];
  const float* conv3_w = (const float*)d_in[6];
  const float* conv3_b = (const float*)d_in[7];
  const float* caps_w  = (const float*)d_in[8];
  const float* caps_b  = (const float*)d_in[9];
  const float* fc1_w   = (const float*)d_in[10];
  const float* fc1_b   = (const float*)d_in[11];
  const float* fc2_w   = (const float*)d_in[12];
  const float* fc2_b   = (const float*)d_in[13];
  const float* fc3_w   = (const float*)d_in[14];
  const float* fc3_b   = (const float*)d_in[15];
  float* out = (float*)d_out;
  float* ws  = (float*)d_ws;

  // ws layout (float units), total 31,866,880 floats = 127.5 MB
  __hip_bfloat16* h1t   = (__hip_bfloat16*)ws;                // 29,491,200 bf16
  __hip_bfloat16* wt2   = (__hip_bfloat16*)(ws + 14745600);   //    819,200 bf16
  __hip_bfloat16* wt3   = (__hip_bfloat16*)(ws + 15155200);   //  1,638,400 bf16
  __hip_bfloat16* h2t   = (__hip_bfloat16*)(ws + 15974400);   //  9,437,184 bf16
  float*          pout  = ws + 20692992;                      //  8,388,608 f32
  __hip_bfloat16* h1f   = (__hip_bfloat16*)(ws + 29081600);   //    524,288 bf16
  __hip_bfloat16* h2f   = (__hip_bfloat16*)(ws + 29343744);   //  1,048,576 bf16
  __hip_bfloat16* wf2   = (__hip_bfloat16*)(ws + 29868032);   //    524,288 bf16
  __hip_bfloat16* wf3   = (__hip_bfloat16*)(ws + 30130176);   //  3,145,728 bf16
  __hip_bfloat16* cwt   = (__hip_bfloat16*)(ws + 31703040);   //    163,840 bf16
  float*          fc1wt = ws + 31784960;                      //     81,920 f32

  prepc1_kernel<<<dim3(16320), 256, 0, stream>>>(
      x, conv1_w, conv1_b, h1t,
      conv2_w, conv3_w, caps_w, fc1_w, fc2_w, fc3_w,
      wt2, wt3, cwt, fc1wt, wf2, wf3);
  conv2_mfma_v6_kernel<<<dim3(256), 768, 0, stream>>>(h1t, wt2, conv2_b, h2t);
  conv3_mfma_kernel<<<dim3(64, 8), 512, 0, stream>>>(h2t, wt3, pout);
  caps_kernel<<<dim3(1024),        256, 0, stream>>>(pout, cwt, caps_b, conv3_b,
                                                     y, fc1wt, fc1_b, out, h1f);
  fc_mfma_kernel<0,2,2><<<dim3(16, 16), 256, 0, stream>>>(
      h1f, wf2, fc2_b, h2f, 1024, 1024, 512);
  fc_mfma_kernel<1,2,2><<<dim3(16, 48), 256, 0, stream>>>(
      h2f, wf3, fc3_b, out + 10240, 1024, 3072, 1024);
}

// Round 15
// 325.164 us; speedup vs baseline: 1.0750x; 1.0750x over previous
//
#include <hip/hip_runtime.h>
#include <hip/hip_bf16.h>
#include <math.h>

#define EPSF 1e-7f

typedef __attribute__((ext_vector_type(8))) short bhalf8;   // 8 bf16 (4 VGPRs)
typedef __attribute__((ext_vector_type(4))) float floatx4;  // MFMA acc

// ============================================================================
// prepc1 (R21): conv1 + all weight prep fused into ONE launch.
// conv1 = R15 form (LDS-broadcast weights + chunk-major stores).
// h1t layout: [img][chunk c16=oc/8][pos][8 oc], chunk stride 3600B.
// ============================================================================
__global__ __launch_bounds__(256) void prepc1_kernel(
    const float* __restrict__ x,      const float* __restrict__ conv1w,
    const float* __restrict__ conv1b, __hip_bfloat16* __restrict__ h1t,
    const float* __restrict__ conv2w, const float* __restrict__ conv3w,
    const float* __restrict__ capsw,  const float* __restrict__ fc1w,
    const float* __restrict__ fc2w,   const float* __restrict__ fc3w,
    __hip_bfloat16* __restrict__ wt2, __hip_bfloat16* __restrict__ wt3,
    __hip_bfloat16* __restrict__ cwt, float* __restrict__ fc1wt,
    __hip_bfloat16* __restrict__ wf2, __hip_bfloat16* __restrict__ wf3)
{
  __shared__ float sh[6400];            // 25.6 KB union
  const int t = threadIdx.x;
  int b = blockIdx.x;

  if (b < 512) {                        // ---- conv1 (R15): 2 img/block ----
    float* wl = sh;                     // [128 oc][32 taps padded]
    float* bl = sh + 4096;
    const int b0 = b * 2;
    for (int i = t; i < 4096; i += 256) {
      int oc = i >> 5, q = i & 31;
      wl[i] = (q < 27) ? conv1w[oc*27 + q] : 0.f;
    }
    if (t < 128) bl[t] = conv1b[t];
    __syncthreads();
    if (t >= 225) return;
    const int py = t / 15, px = t % 15;
    float win[2][28];
    win[0][27] = 0.f; win[1][27] = 0.f;
#pragma unroll
    for (int im = 0; im < 2; ++im) {
      const float* xb = x + (size_t)(b0 + im) * 3072;
#pragma unroll
      for (int c = 0; c < 3; ++c)
#pragma unroll
        for (int ky = 0; ky < 3; ++ky)
#pragma unroll
          for (int kx = 0; kx < 3; ++kx)
            win[im][c*9 + ky*3 + kx] = xb[c*1024 + (py*2 + ky)*32 + (px*2 + kx)];
    }
#pragma unroll 1
    for (int oc0 = 0; oc0 < 128; oc0 += 32) {
      __hip_bfloat16 hv[2][32];
#pragma unroll
      for (int oc = 0; oc < 32; ++oc) {
        const float4* wp = (const float4*)&wl[(oc0 + oc) << 5];  // uniform
        float a0 = bl[oc0 + oc], a1 = a0;
#pragma unroll
        for (int qq = 0; qq < 7; ++qq) {
          float4 wv = wp[qq];                                     // b128 bcast
          a0 = fmaf(win[0][qq*4+0], wv.x, a0); a1 = fmaf(win[1][qq*4+0], wv.x, a1);
          a0 = fmaf(win[0][qq*4+1], wv.y, a0); a1 = fmaf(win[1][qq*4+1], wv.y, a1);
          a0 = fmaf(win[0][qq*4+2], wv.z, a0); a1 = fmaf(win[1][qq*4+2], wv.z, a1);
          a0 = fmaf(win[0][qq*4+3], wv.w, a0); a1 = fmaf(win[1][qq*4+3], wv.w, a1);
        }
        hv[0][oc] = __float2bfloat16(fmaxf(a0, 0.f));
        hv[1][oc] = __float2bfloat16(fmaxf(a1, 0.f));
      }
#pragma unroll
      for (int qq = 0; qq < 4; ++qq) {
        int c16 = (oc0 >> 3) + qq;            // 16B chunk = 8 oc
#pragma unroll
        for (int im = 0; im < 2; ++im) {
          const uint4* src = (const uint4*)hv[im];
          *(uint4*)((char*)h1t + (size_t)(b0+im)*57600 + c16*3600 + t*16) = src[qq];
        }
      }
    }
    return;
  }
  b -= 512;
  if (b < 12288) {                      // fc3_w cast: 3,145,728
    int i = b*256 + t;
    wf3[i] = __float2bfloat16(fc3w[i]);
    return;
  }
  b -= 12288;
  if (b < 2048) {                       // fc2_w cast: 524,288
    int i = b*256 + t;
    wf2[i] = __float2bfloat16(fc2w[i]);
    return;
  }
  b -= 2048;
  if (b < 640) {                        // caps_w transpose: 163,840
    int i2 = b*256 + t;
    int k = i2 & 15, j = (i2 >> 4) & 15, io = i2 >> 8;
    cwt[i2] = __float2bfloat16(capsw[(io*16 + k)*16 + j]);
    return;
  }
  b -= 640;
  if (b < 320) {                        // fc1_w transpose: 81,920
    int i = b*256 + t;
    int j = i >> 9, n = i & 511;
    fc1wt[i] = fc1w[n*160 + j];
    return;
  }
  b -= 320;
  if (b < 256) {                        // wtrans3: one oc per block
    float* tl = sh;
    const float* src = conv3w + (size_t)b*6400;   // contiguous per oc
    for (int i = t; i < 6400; i += 256) tl[i] = src[i];
    __syncthreads();
#pragma unroll 1
    for (int q = 0; q < 25; ++q) {
      int j = q*256 + t;                // flat k = s*64+kq = j
      int s = j >> 6, kq = j & 63;
      int tap = j >> 8, ic = j & 255;
      wt3[(size_t)s*16384 + b*64 + kq] = __float2bfloat16(tl[ic*25 + tap]);
    }
    return;
  }
  b -= 256;
  {                                     // wtrans2: one oc per block (256)
    float* tl = sh;
    const float* src = conv2w + (size_t)b*3200;   // contiguous per oc
    for (int i = t; i < 3200; i += 256) tl[i] = src[i];
    __syncthreads();
#pragma unroll 1
    for (int q = 0; q < 13; ++q) {
      int j = q*256 + t;
      if (j < 3200) {
        int s = j >> 5, kq = j & 31;
        int h = (s >= 50) ? 1 : 0;
        int r2 = s - h*50;
        int tap = r2 >> 1, qq = r2 & 1;
        int ic = h*64 + qq*32 + kq;
        wt2[(size_t)s*8192 + b*32 + kq] = __float2bfloat16(tl[ic*25 + tap]);
      }
    }
  }
}

// ============================================================================
// conv2_mfma_v2 (FINAL): 256 blocks x 1024 thr, 4 img/block, 1 block/CU,
// 16 waves = 2wm x 8wn, Nt=2, 2-slot-set B register pipeline.
// Measured floor of this family: 70.4 us (VGPR 52, no spill, conflicts at
// structural b128 floor). Six geometries measured: 70.4 (this) / 75.5 (8w
// Nt4) / 91.5 (12w Nt4) / 113.7 (v5 full) / 121.6-equiv (v5 1-blk) /
// 151 (4-set spill). dur x waves/CU ~ const -> per-wave latency-bound;
// 16 waves is the TLP maximum within the LDS envelope.
// ============================================================================
__global__ __launch_bounds__(1024) void conv2_mfma_v2_kernel(
    const __hip_bfloat16* __restrict__ a,   // h1t chunk-major
    const __hip_bfloat16* __restrict__ wt,  // wt2 dense [100][256][32]
    const float* __restrict__ bias,
    __hip_bfloat16* __restrict__ out,       // h2t [1024][36][256]
    int img_base)
{
  __shared__ __align__(16) unsigned short Il[4*225*64];   // 115,200 B
  const int b0   = img_base + blockIdx.x * 4;
  const int t    = threadIdx.x;
  const int lane = t & 63;
  const int w    = t >> 6;        // 0..15
  const int wm   = w >> 3;        // 0..1 : M-group (tiles 0..4 / 5..8)
  const int wn   = w & 7;         // 0..7 : oc group wn*32 (Nt=2)
  const int n    = lane & 15;
  const int g    = lane >> 4;

  const char* gB = (const char*)wt + (wn*32 + n)*64 + g*16;
  bhalf8 b00 = *(const bhalf8*)(gB);                  // s=0
  bhalf8 b01 = *(const bhalf8*)(gB + 1024);
  bhalf8 b10 = *(const bhalf8*)(gB + 16384);          // s=1
  bhalf8 b11 = *(const bhalf8*)(gB + 16384 + 1024);

  int Abase[5], em[5];
#pragma unroll
  for (int mt = 0; mt < 5; ++mt) {
    int tile = wm*5 + mt;
    int m = tile*16 + n;
    if (m >= 144) m = 0;                 // wm=1, mt=4 unused
    int img = m / 36, pos = m - img*36;
    int py = pos / 6, px = pos - py*6;
    int pixb = 30*py + 2*px;             // always even
    Abase[mt] = (img*225 + pixb) * 128;  // bytes (row = 64 ic = 128 B)
    em[mt] = g + m;                      // slot seed: (g + m + dsw) & 7
  }

  floatx4 acc[5][2];
#pragma unroll
  for (int mt = 0; mt < 5; ++mt)
#pragma unroll
    for (int nt = 0; nt < 2; ++nt)
      acc[mt][nt] = (floatx4){0.f, 0.f, 0.f, 0.f};

  int s = 0;
#pragma unroll 1
  for (int h = 0; h < 2; ++h) {
    if (h) __syncthreads();
    for (int i = t; i < 7200; i += 1024) {
      int img = i / 1800;
      int r = i - img*1800;
      int p = r >> 3, c = r & 7;
      uint4 v = *(const uint4*)((const char*)a +
                (size_t)(b0+img)*57600 + (h*8 + c)*3600 + p*16);
      int px15 = p % 15, py15 = p / 15;
      int csw = (c + (px15 >> 1) + 6*(py15 >> 1) + ((img & 1) << 2)) & 7;
      *(uint4*)((char*)Il + (img*225 + p)*128 + csw*16) = v;
    }
    __syncthreads();

    int dpix = 0, kx = 0, ky = 0;        // dpix = ky*15 + kx
#pragma unroll 1
    for (int tap = 0; tap < 25; ++tap) {
      const int doff = dpix << 7;
      const int dsw  = (kx >> 1) + 6*(ky >> 1);
      int a0[5];
#pragma unroll
      for (int mt = 0; mt < 5; ++mt)
        a0[mt] = Abase[mt] + doff + (((em[mt] + dsw) & 7) << 4);

      // ---- q = 0 (slot set 0) ----
#pragma unroll
      for (int mt = 0; mt < 4; ++mt) {
        bhalf8 av = *(const bhalf8*)((const char*)Il + a0[mt]);
        acc[mt][0] = __builtin_amdgcn_mfma_f32_16x16x32_bf16(av, b00, acc[mt][0], 0, 0, 0);
        acc[mt][1] = __builtin_amdgcn_mfma_f32_16x16x32_bf16(av, b01, acc[mt][1], 0, 0, 0);
      }
      if (wm == 0) {
        bhalf8 av = *(const bhalf8*)((const char*)Il + a0[4]);
        acc[4][0] = __builtin_amdgcn_mfma_f32_16x16x32_bf16(av, b00, acc[4][0], 0, 0, 0);
        acc[4][1] = __builtin_amdgcn_mfma_f32_16x16x32_bf16(av, b01, acc[4][1], 0, 0, 0);
      }
      {
        const int spre = (s + 2 < 100) ? (s + 2) : 99;
        b00 = *(const bhalf8*)(gB + (size_t)spre*16384);
        b01 = *(const bhalf8*)(gB + (size_t)spre*16384 + 1024);
      }
      // ---- q = 1 (slot set 1): addr ^ 64 ----
#pragma unroll
      for (int mt = 0; mt < 4; ++mt) {
        bhalf8 av = *(const bhalf8*)((const char*)Il + (a0[mt] ^ 64));
        acc[mt][0] = __builtin_amdgcn_mfma_f32_16x16x32_bf16(av, b10, acc[mt][0], 0, 0, 0);
        acc[mt][1] = __builtin_amdgcn_mfma_f32_16x16x32_bf16(av, b11, acc[mt][1], 0, 0, 0);
      }
      if (wm == 0) {
        bhalf8 av = *(const bhalf8*)((const char*)Il + (a0[4] ^ 64));
        acc[4][0] = __builtin_amdgcn_mfma_f32_16x16x32_bf16(av, b10, acc[4][0], 0, 0, 0);
        acc[4][1] = __builtin_amdgcn_mfma_f32_16x16x32_bf16(av, b11, acc[4][1], 0, 0, 0);
      }
      {
        const int spre = (s + 3 < 100) ? (s + 3) : 99;
        b10 = *(const bhalf8*)(gB + (size_t)spre*16384);
        b11 = *(const bhalf8*)(gB + (size_t)spre*16384 + 1024);
      }
      s += 2;
      if (kx == 4) { kx = 0; ++ky; dpix += 11; } else { ++kx; ++dpix; }
    }
  }

  const float bv0 = bias[wn*32 + n];
  const float bv1 = bias[wn*32 + 16 + n];
#pragma unroll
  for (int mt = 0; mt < 5; ++mt) {
    if (mt < 4 || wm == 0) {
      int tile = wm*5 + mt;
#pragma unroll
      for (int r = 0; r < 4; ++r) {
        int m = tile*16 + g*4 + r;
        int img = m / 36, pos = m - img*36;
        size_t o = (((size_t)(b0+img)*36 + pos) << 8) + wn*32 + n;
        out[o]      = __float2bfloat16(fmaxf(acc[mt][0][r] + bv0, 0.f));
        out[o + 16] = __float2bfloat16(fmaxf(acc[mt][1][r] + bv1, 0.f));
      }
    }
  }
}

// ============================================================================
// conv3_mfma (split-K): h2t -> fp32 partials pout[8][1024][256][4].
// ============================================================================
__global__ __launch_bounds__(512) void conv3_mfma_kernel(
    const __hip_bfloat16* __restrict__ a,   // h2t [1024][36][256]
    const __hip_bfloat16* __restrict__ wt,  // wt3 dense [100][256][64]
    float* __restrict__ pout)               // [8][1024*1024]
{
  __shared__ __align__(16) unsigned short Il[16*1448];    // 46,336 B
  const int b0   = blockIdx.x * 16;
  const int kq   = blockIdx.y;             // ic slice kq*32..+31
  const int t    = threadIdx.x;
  const int lane = t & 63;
  const int w    = t >> 6;                 // 0..7 -> oc w*32
  const int n    = lane & 15;
  const int g    = lane >> 4;

  for (int i = t; i < 2304; i += 512) {    // 16*36*4 chunks of 16B
    int img = i / 144, r = i - img*144;
    int p = r >> 2, c = r & 3;
    uint4 v = *(const uint4*)((const char*)a +
              ((((size_t)(b0+img)*36 + p) << 9) + kq*64 + c*16));
    *(uint4*)((char*)Il + (img*1448 + p*40 + c*8)*2) = v;
  }

  const char* gB = (const char*)wt + (size_t)(w*32 + n)*128 +
                   (kq & 1)*64 + g*16;
  const int kqs = kq >> 1;
  bhalf8 b00, b01, b10, b11;
  b00 = *(const bhalf8*)(gB + (size_t)(0*4 + kqs)*32768);
  b01 = *(const bhalf8*)(gB + (size_t)(0*4 + kqs)*32768 + 2048);
  b10 = *(const bhalf8*)(gB + (size_t)(1*4 + kqs)*32768);
  b11 = *(const bhalf8*)(gB + (size_t)(1*4 + kqs)*32768 + 2048);

  const int d = n >> 2, pos = n & 3;
  const int pb = (pos >> 1)*6 + (pos & 1);
  int ab[4];
#pragma unroll
  for (int mt = 0; mt < 4; ++mt)
    ab[mt] = ((mt*4 + d)*1448 + pb*40 + g*8) * 2;   // bytes

  floatx4 acc[4][2];
#pragma unroll
  for (int mt = 0; mt < 4; ++mt)
#pragma unroll
    for (int nt = 0; nt < 2; ++nt)
      acc[mt][nt] = (floatx4){0.f, 0.f, 0.f, 0.f};

  __syncthreads();   // the ONLY barrier

  int toff = 0, kx = 0;
#pragma unroll 1
  for (int tap = 0; tap < 24; tap += 2) {
#pragma unroll
    for (int mt = 0; mt < 4; ++mt) {
      bhalf8 av = *(const bhalf8*)((const char*)Il + ab[mt] + toff*80);
      acc[mt][0] = __builtin_amdgcn_mfma_f32_16x16x32_bf16(av, b00, acc[mt][0], 0, 0, 0);
      acc[mt][1] = __builtin_amdgcn_mfma_f32_16x16x32_bf16(av, b01, acc[mt][1], 0, 0, 0);
    }
    b00 = *(const bhalf8*)(gB + (size_t)((tap+2)*4 + kqs)*32768);
    b01 = *(const bhalf8*)(gB + (size_t)((tap+2)*4 + kqs)*32768 + 2048);
    if (++kx == 5) { kx = 0; toff += 2; } else ++toff;
#pragma unroll
    for (int mt = 0; mt < 4; ++mt) {
      bhalf8 av = *(const bhalf8*)((const char*)Il + ab[mt] + toff*80);
      acc[mt][0] = __builtin_amdgcn_mfma_f32_16x16x32_bf16(av, b10, acc[mt][0], 0, 0, 0);
      acc[mt][1] = __builtin_amdgcn_mfma_f32_16x16x32_bf16(av, b11, acc[mt][1], 0, 0, 0);
    }
    {
      const int tpre = (tap + 3 <= 24) ? (tap + 3) : 24;
      b10 = *(const bhalf8*)(gB + (size_t)(tpre*4 + kqs)*32768);
      b11 = *(const bhalf8*)(gB + (size_t)(tpre*4 + kqs)*32768 + 2048);
    }
    if (++kx == 5) { kx = 0; toff += 2; } else ++toff;
  }
#pragma unroll
  for (int mt = 0; mt < 4; ++mt) {
    bhalf8 av = *(const bhalf8*)((const char*)Il + ab[mt] + toff*80);
    acc[mt][0] = __builtin_amdgcn_mfma_f32_16x16x32_bf16(av, b00, acc[mt][0], 0, 0, 0);
    acc[mt][1] = __builtin_amdgcn_mfma_f32_16x16x32_bf16(av, b01, acc[mt][1], 0, 0, 0);
  }

  float* po = pout + (size_t)kq*1048576;
#pragma unroll
  for (int mt = 0; mt < 4; ++mt) {
#pragma unroll
    for (int r = 0; r < 4; ++r) {
      int m = mt*16 + g*4 + r;
      int img = m >> 2, p2 = m & 3;
#pragma unroll
      for (int nt = 0; nt < 2; ++nt)
        po[((size_t)(b0+img)*256 + w*32 + nt*16 + n)*4 + p2] = acc[mt][nt][r];
    }
  }
}

// ============================================================================
// caps: sum 8 conv3 partials + bias + ReLU -> squash -> u_hat -> routing
// -> v_lengths + fused fc1.
// ============================================================================
__global__ __launch_bounds__(256) void caps_kernel(
    const float* __restrict__ pout, const __hip_bfloat16* __restrict__ cwt,
    const float* __restrict__ cb, const float* __restrict__ c3b,
    const int* __restrict__ y,
    const float* __restrict__ fc1wt, const float* __restrict__ fc1b,
    float* __restrict__ vlen, __hip_bfloat16* __restrict__ h1f)
{
  __shared__ float prim[1024];     // [64][16]
  __shared__ float uh[10240];      // [64][10][16]
  __shared__ float bij[640];
  __shared__ float cij[640];
  __shared__ float vv[160];        // [10][16]
  const int b = blockIdx.x, t = threadIdx.x;
  {
    const float* pp = pout + (size_t)b*1024 + t*4;
    float4 s4 = *(const float4*)pp;
#pragma unroll
    for (int q = 1; q < 8; ++q) {
      float4 v = *(const float4*)(pp + (size_t)q*1048576);
      s4.x += v.x; s4.y += v.y; s4.z += v.z; s4.w += v.w;
    }
    const float bv = c3b[t];       // oc = t
    float4 h = make_float4(fmaxf(s4.x + bv, 0.f), fmaxf(s4.y + bv, 0.f),
                           fmaxf(s4.z + bv, 0.f), fmaxf(s4.w + bv, 0.f));
    float dd = h.x*h.x + h.y*h.y + h.z*h.z + h.w*h.w;
    dd += __shfl_xor(dd, 1);
    dd += __shfl_xor(dd, 2);
    float sc = dd / (1.f + dd) / sqrtf(dd + EPSF);
    float4 o4 = make_float4(h.x*sc, h.y*sc, h.z*sc, h.w*sc);
    *(float4*)&prim[t*4] = o4;     // prim flat elem = t*4..t*4+3
  }
  for (int f = t; f < 640; f += 256) bij[f] = 0.f;
  __syncthreads();
  for (int f = t; f < 10240; f += 256) {
    const int i = f / 160;
    const uint4* wv = (const uint4*)(cwt + (size_t)f*16);
    uint4 wa = wv[0], wb = wv[1];
    unsigned uw[8] = {wa.x, wa.y, wa.z, wa.w, wb.x, wb.y, wb.z, wb.w};
    const float* pp = prim + i*16;
    float s = 0.f;
#pragma unroll
    for (int q = 0; q < 8; ++q) {
      float lo = __uint_as_float(uw[q] << 16);
      float hi = __uint_as_float(uw[q] & 0xffff0000u);
      s = fmaf(pp[2*q],   lo, s);
      s = fmaf(pp[2*q+1], hi, s);
    }
    uh[f] = s;
  }
  __syncthreads();
  for (int r = 0; r < 3; ++r) {
    if (t < 64) {
      float e[10];
      float mx = -1e30f;
#pragma unroll
      for (int o = 0; o < 10; ++o) { e[o] = bij[t*10 + o]; mx = fmaxf(mx, e[o]); }
      float sum = 0.f;
#pragma unroll
      for (int o = 0; o < 10; ++o) { e[o] = expf(e[o] - mx); sum += e[o]; }
      float inv = 1.f / sum;
#pragma unroll
      for (int o = 0; o < 10; ++o) cij[t*10 + o] = e[o] * inv;
    }
    __syncthreads();
    if (t < 160) {
      const int o = t >> 4;
      float s0 = cb[t], s1 = 0.f, s2 = 0.f, s3 = 0.f;
      for (int i = 0; i < 64; i += 4) {
        s0 = fmaf(cij[(i+0)*10 + o], uh[(i+0)*160 + t], s0);
        s1 = fmaf(cij[(i+1)*10 + o], uh[(i+1)*160 + t], s1);
        s2 = fmaf(cij[(i+2)*10 + o], uh[(i+2)*160 + t], s2);
        s3 = fmaf(cij[(i+3)*10 + o], uh[(i+3)*160 + t], s3);
      }
      float s = (s0 + s1) + (s2 + s3);
      float dd = s*s;
      dd += __shfl_xor(dd, 1); dd += __shfl_xor(dd, 2);
      dd += __shfl_xor(dd, 4); dd += __shfl_xor(dd, 8);
      float sc = dd / (1.f + dd) / sqrtf(dd + EPSF);
      vv[t] = s * sc;
      if (r == 2 && (t & 15) == 0)
        vlen[b*10 + o] = sqrtf(sc*sc*dd + EPSF);
    }
    __syncthreads();
    if (r < 2) {
      for (int f = t; f < 640; f += 256) {
        int i = f / 10, o = f % 10;
        const float* up = &uh[i*160 + o*16];
        const float* vp = &vv[o*16];
        float a = 0.f;
#pragma unroll
        for (int j = 0; j < 16; ++j) a = fmaf(up[j], vp[j], a);
        bij[f] += a;
      }
      __syncthreads();
    }
  }
  const int yb = y[b];
  const float* vy = &vv[yb*16];
  for (int nn = t; nn < 512; nn += 256) {
    float s = fc1b[nn];
#pragma unroll
    for (int k = 0; k < 16; ++k)
      s = fmaf(vy[k], fc1wt[(yb*16 + k)*512 + nn], s);
    h1f[b*512 + nn] = __float2bfloat16(fmaxf(s, 0.f));
  }
}

// ============================================================================
// fc_mfma: out = act(A[M,K]bf16 @ W[N,K]bf16^T + bias). Pure-register GEMM.
// ============================================================================
template<int ACT, int MT, int NT>
__global__ __launch_bounds__(256) void fc_mfma_kernel(
    const __hip_bfloat16* __restrict__ A,   // [M,K]
    const __hip_bfloat16* __restrict__ W,   // [N,K]
    const float* __restrict__ bias,
    void* __restrict__ outv, int M, int N, int K)
{
  const int t    = threadIdx.x;
  const int lane = t & 63;
  const int w    = t >> 6;
  const int wr   = w >> 1, wc = w & 1;
  const int n    = lane & 15, g = lane >> 4;
  const int m0   = blockIdx.x * (2*MT*16) + wr*(MT*16);
  const int n0   = blockIdx.y * (2*NT*16) + wc*(NT*16);
  const __hip_bfloat16* Ap = A + (size_t)(m0 + n)*K + g*8;
  const __hip_bfloat16* Wp = W + (size_t)(n0 + n)*K + g*8;
  const int steps = K >> 5;

  bhalf8 aa0[MT], aa1[MT], bb0[NT], bb1[NT];
#pragma unroll
  for (int mt = 0; mt < MT; ++mt) {
    aa0[mt] = *(const bhalf8*)(Ap + (size_t)mt*16*K);
    aa1[mt] = *(const bhalf8*)(Ap + (size_t)mt*16*K + 32);
  }
#pragma unroll
  for (int nt = 0; nt < NT; ++nt) {
    bb0[nt] = *(const bhalf8*)(Wp + (size_t)nt*16*K);
    bb1[nt] = *(const bhalf8*)(Wp + (size_t)nt*16*K + 32);
  }

  floatx4 acc[MT][NT];
#pragma unroll
  for (int mt = 0; mt < MT; ++mt)
#pragma unroll
    for (int nt = 0; nt < NT; ++nt)
      acc[mt][nt] = (floatx4){0.f, 0.f, 0.f, 0.f};

#pragma unroll 1
  for (int s = 0; s < steps; s += 2) {
#pragma unroll
    for (int mt = 0; mt < MT; ++mt)
#pragma unroll
      for (int nt = 0; nt < NT; ++nt)
        acc[mt][nt] = __builtin_amdgcn_mfma_f32_16x16x32_bf16(
            aa0[mt], bb0[nt], acc[mt][nt], 0, 0, 0);
    {
      const int spre = (s + 2 < steps) ? (s + 2) : s;
#pragma unroll
      for (int mt = 0; mt < MT; ++mt)
        aa0[mt] = *(const bhalf8*)(Ap + (size_t)mt*16*K + spre*32);
#pragma unroll
      for (int nt = 0; nt < NT; ++nt)
        bb0[nt] = *(const bhalf8*)(Wp + (size_t)nt*16*K + spre*32);
    }
#pragma unroll
    for (int mt = 0; mt < MT; ++mt)
#pragma unroll
      for (int nt = 0; nt < NT; ++nt)
        acc[mt][nt] = __builtin_amdgcn_mfma_f32_16x16x32_bf16(
            aa1[mt], bb1[nt], acc[mt][nt], 0, 0, 0);
    {
      const int spre = (s + 3 < steps) ? (s + 3) : (s + 1);
#pragma unroll
      for (int mt = 0; mt < MT; ++mt)
        aa1[mt] = *(const bhalf8*)(Ap + (size_t)mt*16*K + spre*32);
#pragma unroll
      for (int nt = 0; nt < NT; ++nt)
        bb1[nt] = *(const bhalf8*)(Wp + (size_t)nt*16*K + spre*32);
    }
  }

#pragma unroll
  for (int mt = 0; mt < MT; ++mt) {
#pragma unroll
    for (int r = 0; r < 4; ++r) {
      const int m = m0 + mt*16 + g*4 + r;
#pragma unroll
      for (int nt = 0; nt < NT; ++nt) {
        const int col = n0 + nt*16 + n;
        float v = acc[mt][nt][r] + bias[col];
        if (ACT == 0) {
          ((__hip_bfloat16*)outv)[(size_t)m*N + col] =
              __float2bfloat16(fmaxf(v, 0.f));
        } else {
          ((float*)outv)[(size_t)m*N + col] = 1.f / (1.f + expf(-v));
        }
      }
    }
  }
}

// ============================================================================
extern "C" void kernel_launch(void* const* d_in, const int* in_sizes, int n_in,
                              void* d_out, int out_size, void* d_ws, size_t ws_size,
                              hipStream_t stream) {
  const float* x       = (const float*)d_in[0];
  const int*   y       = (const int*)  d_in[1];
  const float* conv1_w = (const float*)d_in[2];
  const float* conv1_b = (const float*)d_in[3];
  const float* conv2_w = (const float*)d_in[4];
  const float* conv2_b = (const float*)d_in[5];
  const float* conv3_w = (const float*)d_in[6];
  const float* conv3_b = (const float*)d_in[7];
  const float* caps_w  = (const float*)d_in[8];
  const float* caps_b  = (const float*)d_in[9];
  const float* fc1_w   = (const float*)d_in[10];
  const float* fc1_b   = (const float*)d_in[11];
  const float* fc2_w   = (const float*)d_in[12];
  const float* fc2_b   = (const float*)d_in[13];
  const float* fc3_w   = (const float*)d_in[14];
  const float* fc3_b   = (const float*)d_in[15];
  float* out = (float*)d_out;
  float* ws  = (float*)d_ws;

  // ws layout (float units), total 31,866,880 floats = 127.5 MB
  __hip_bfloat16* h1t   = (__hip_bfloat16*)ws;                // 29,491,200 bf16
  __hip_bfloat16* wt2   = (__hip_bfloat16*)(ws + 14745600);   //    819,200 bf16
  __hip_bfloat16* wt3   = (__hip_bfloat16*)(ws + 15155200);   //  1,638,400 bf16
  __hip_bfloat16* h2t   = (__hip_bfloat16*)(ws + 15974400);   //  9,437,184 bf16
  float*          pout  = ws + 20692992;                      //  8,388,608 f32
  __hip_bfloat16* h1f   = (__hip_bfloat16*)(ws + 29081600);   //    524,288 bf16
  __hip_bfloat16* h2f   = (__hip_bfloat16*)(ws + 29343744);   //  1,048,576 bf16
  __hip_bfloat16* wf2   = (__hip_bfloat16*)(ws + 29868032);   //    524,288 bf16
  __hip_bfloat16* wf3   = (__hip_bfloat16*)(ws + 30130176);   //  3,145,728 bf16
  __hip_bfloat16* cwt   = (__hip_bfloat16*)(ws + 31703040);   //    163,840 bf16
  float*          fc1wt = ws + 31784960;                      //     81,920 f32

  prepc1_kernel<<<dim3(16320), 256, 0, stream>>>(
      x, conv1_w, conv1_b, h1t,
      conv2_w, conv3_w, caps_w, fc1_w, fc2_w, fc3_w,
      wt2, wt3, cwt, fc1wt, wf2, wf3);
  conv2_mfma_v2_kernel<<<dim3(256), 1024, 0, stream>>>(h1t, wt2, conv2_b, h2t, 0);
  conv3_mfma_kernel<<<dim3(64, 8), 512, 0, stream>>>(h2t, wt3, pout);
  caps_kernel<<<dim3(1024),        256, 0, stream>>>(pout, cwt, caps_b, conv3_b,
                                                     y, fc1wt, fc1_b, out, h1f);
  fc_mfma_kernel<0,2,2><<<dim3(16, 16), 256, 0, stream>>>(
      h1f, wf2, fc2_b, h2f, 1024, 1024, 512);
  fc_mfma_kernel<1,2,2><<<dim3(16, 48), 256, 0, stream>>>(
      h2f, wf3, fc3_b, out + 10240, 1024, 3072, 1024);
}